// Round 2
// 123.873 us; speedup vs baseline: 1.0165x; 1.0165x over previous
//
#include <hip/hip_runtime.h>
#include <stdint.h>

// 7x7 conv, stride 1, pad 3, on 64 x 512 x 512 fp32 (single channel).
// out[n,y,x] = sum_{ky,kx} x[n, y+ky-3, x+kx-3] * w[ky,kx]
//
// R9: R8's linear-LDS + global_load_lds + b128 plan, with the staging
// restructured so every global_load_lds runs FULL-EXEC.
//   - R8 FAILED (absmax 102): global_load_lds writes LDS at (first-active-
//     lane base + lane_id*16). The per-lane OOB guard diverged within waves
//     at tile borders -> base taken from a non-zero lane -> all writes
//     shifted -> corrupted tile. (Guide m104/m108 caveat.)
//   - Fix: stage per ROW. One wave stages f4 slots c4=1..64 of a row with a
//     single unguarded global_load_lds (gx = bx + 4*lane, always in-bounds
//     in x). The only guard is gy, which is WAVE-UNIFORM (per-row) -> OOB
//     rows zero-fill with a full-wave contiguous ds_write_b128.
//   - The 44 halo f4s (c4=0 and c4=65 per row) use a normal guarded VGPR
//     float4 load + ds_write_b128 from tid<44 (divergence harmless there).
//   - Compute: 3 overlapping ds_read_b128 per row (lanes span contiguous
//     1 KiB -> conflict-free), identical FMA order to the passing R7.

#define IMG_W 512
#define IMG_H 512
#define NIMG  64
#define TW    256            // output tile width per block
#define TH    16             // output tile height per block
#define HALO  3
#define LDS_W 264            // floats per row: tile col c <-> global x = bx-4+c
#define LDS_H (TH + 2*HALO)  // 22 rows

// async 16B global -> LDS (dest must be uniform base + lane*16, FULL exec)
__device__ __forceinline__ void gload_lds16(const float* src, float* dst_lds)
{
    __builtin_amdgcn_global_load_lds(
        (__attribute__((address_space(1))) void*)(uintptr_t)src,
        (__attribute__((address_space(3))) void*)(uintptr_t)dst_lds,
        16, 0, 0);
}

__global__ __launch_bounds__(256, 6) void conv7x7_kernel(
    const float* __restrict__ x,
    const float* __restrict__ wgt,
    float* __restrict__ out)
{
    __shared__ float tile[LDS_H * LDS_W];   // 23,232 B, linear

    const int tid  = threadIdx.x;
    const int wave = tid >> 6;
    const int lane = tid & 63;
    const int bx   = blockIdx.x * TW;
    const int by   = blockIdx.y * TH;
    const int n    = blockIdx.z;

    const float* img = x + (size_t)n * (IMG_W * IMG_H);

    // ---- weights: wave-uniform -> SGPRs (s_loads overlap staging) ----
    float w[49];
    #pragma unroll
    for (int i = 0; i < 49; ++i) w[i] = wgt[i];

    // ---- stage interior: per row, one full wave, c4=1..64 (cols 4..259) ----
    // gx = bx + 4*lane in [bx, bx+255]: always in-bounds in x.
    // gy guard is wave-uniform -> exec stays full for every global_load_lds.
    for (int r = wave; r < LDS_H; r += 4) {
        const int gy = by - HALO + r;
        float* dst = &tile[r * LDS_W + 4 + 4 * lane];
        if ((unsigned)gy < IMG_H) {
            gload_lds16(&img[(size_t)gy * IMG_W + bx + 4 * lane], dst);
        } else {
            *(float4*)dst = make_float4(0.f, 0.f, 0.f, 0.f);  // contiguous b128
        }
    }

    // ---- stage edges: 2 halo f4 per row (cols 0..3 and 260..263) ----
    if (tid < 2 * LDS_H) {
        const int r    = tid >> 1;
        const int side = tid & 1;
        const int cb   = side ? (LDS_W - 4) : 0;   // float col base in tile
        const int gx   = side ? (bx + 256) : (bx - 4);
        const int gy   = by - HALO + r;
        float4 v = make_float4(0.f, 0.f, 0.f, 0.f);
        if (((unsigned)gy < IMG_H) && ((unsigned)gx < IMG_W))
            v = *(const float4*)&img[(size_t)gy * IMG_W + gx];
        *(float4*)&tile[r * LDS_W + cb] = v;
    }

    __syncthreads();   // drains vmcnt (global_load_lds) + lgkmcnt

    // ---- compute: 4x x 4y outputs per thread, 3 ds_read_b128 per row ----
    const int lx = lane * 4;        // output x within tile
    const int rbase = wave * 4;

    float acc[4][4] = {};

    #pragma unroll
    for (int r = 0; r < 10; ++r) {
        const float* rowp = &tile[(rbase + r) * LDS_W + lx];
        // lanes read contiguous 1 KiB per instruction -> conflict-free b128
        const float4 a = *(const float4*)(rowp + 0);
        const float4 b = *(const float4*)(rowp + 4);
        const float4 c = *(const float4*)(rowp + 8);
        const float row[12] = {a.x, a.y, a.z, a.w,
                               b.x, b.y, b.z, b.w,
                               c.x, c.y, c.z, c.w};
        #pragma unroll
        for (int j = 0; j < 4; ++j) {
            const int ky = r - j;
            if (ky >= 0 && ky < 7) {
                #pragma unroll
                for (int kx = 0; kx < 7; ++kx) {
                    const float wv = w[ky * 7 + kx];
                    #pragma unroll
                    for (int cc = 0; cc < 4; ++cc)
                        acc[j][cc] = fmaf(row[1 + kx + cc], wv, acc[j][cc]);
                }
            }
        }
    }

    // ---- store: 4 rows of float4 per thread (contiguous per wave) ----
    float* o = out + (size_t)n * (IMG_W * IMG_H);
    #pragma unroll
    for (int j = 0; j < 4; ++j) {
        float4 v = make_float4(acc[j][0], acc[j][1], acc[j][2], acc[j][3]);
        *(float4*)&o[(size_t)(by + rbase + j) * IMG_W + bx + lx] = v;
    }
}

extern "C" void kernel_launch(void* const* d_in, const int* in_sizes, int n_in,
                              void* d_out, int out_size, void* d_ws, size_t ws_size,
                              hipStream_t stream)
{
    const float* x   = (const float*)d_in[0];
    const float* wgt = (const float*)d_in[1];
    float* out       = (float*)d_out;

    dim3 grid(IMG_W / TW, IMG_H / TH, NIMG);   // 2 x 32 x 64 = 4096 blocks
    conv7x7_kernel<<<grid, 256, 0, stream>>>(x, wgt, out);
}

// Round 3
// 117.636 us; speedup vs baseline: 1.0704x; 1.0530x over previous
//
#include <hip/hip_runtime.h>
#include <stdint.h>

// 7x7 conv, stride 1, pad 3, on 64 x 512 x 512 fp32 (single channel).
// out[n,y,x] = sum_{ky,kx} x[n, y+ky-3, x+kx-3] * w[ky,kx]
//
// R10: R9 with compute LDS reads split b128 -> b64.
//   - R9 counters: SQ_LDS_BANK_CONFLICT 1.14e7 cyc (= +23 cyc per b128,
//     ~45% of runtime). Wave64 ds_read_b128 presents 4 dwords/lane ->
//     4 accesses/bank per 32-lane phase: an INTRINSIC ~4-way conflict
//     (matches m134: b128 85 B/cyc vs 128 peak; and m98 GEMM's 1.7e7).
//   - Contiguous ds_read_b64 is 2 dwords/lane -> 2/bank = the measured-free
//     2-way case. 6 b64 per row replace 3 b128.
//   - hipcc's vectorizer would re-merge adjacent float2 loads into b128
//     (base provably 16B-aligned). The six 8-byte deltas are laundered
//     through empty inline asm so no two loads are provably adjacent; the
//     loads stay ordinary IR loads (compiler manages lgkmcnt as usual).
//   - Staging (full-exec global_load_lds, R9) / FMA order / store unchanged.

#define IMG_W 512
#define IMG_H 512
#define NIMG  64
#define TW    256            // output tile width per block
#define TH    16             // output tile height per block
#define HALO  3
#define LDS_W 264            // floats per row: tile col c <-> global x = bx-4+c
#define LDS_H (TH + 2*HALO)  // 22 rows

// async 16B global -> LDS (dest must be uniform base + lane*16, FULL exec)
__device__ __forceinline__ void gload_lds16(const float* src, float* dst_lds)
{
    __builtin_amdgcn_global_load_lds(
        (__attribute__((address_space(1))) void*)(uintptr_t)src,
        (__attribute__((address_space(3))) void*)(uintptr_t)dst_lds,
        16, 0, 0);
}

__global__ __launch_bounds__(256, 6) void conv7x7_kernel(
    const float* __restrict__ x,
    const float* __restrict__ wgt,
    float* __restrict__ out)
{
    __shared__ float tile[LDS_H * LDS_W];   // 23,232 B, linear

    const int tid  = threadIdx.x;
    const int wave = tid >> 6;
    const int lane = tid & 63;
    const int bx   = blockIdx.x * TW;
    const int by   = blockIdx.y * TH;
    const int n    = blockIdx.z;

    const float* img = x + (size_t)n * (IMG_W * IMG_H);

    // ---- weights: wave-uniform -> SGPRs (s_loads overlap staging) ----
    float w[49];
    #pragma unroll
    for (int i = 0; i < 49; ++i) w[i] = wgt[i];

    // ---- stage interior: per row, one full wave, c4=1..64 (cols 4..259) ----
    // gx = bx + 4*lane in [bx, bx+255]: always in-bounds in x.
    // gy guard is wave-uniform -> exec stays full for every global_load_lds.
    for (int r = wave; r < LDS_H; r += 4) {
        const int gy = by - HALO + r;
        float* dst = &tile[r * LDS_W + 4 + 4 * lane];
        if ((unsigned)gy < IMG_H) {
            gload_lds16(&img[(size_t)gy * IMG_W + bx + 4 * lane], dst);
        } else {
            *(float4*)dst = make_float4(0.f, 0.f, 0.f, 0.f);  // contiguous write
        }
    }

    // ---- stage edges: 2 halo f4 per row (cols 0..3 and 260..263) ----
    if (tid < 2 * LDS_H) {
        const int r    = tid >> 1;
        const int side = tid & 1;
        const int cb   = side ? (LDS_W - 4) : 0;   // float col base in tile
        const int gx   = side ? (bx + 256) : (bx - 4);
        const int gy   = by - HALO + r;
        float4 v = make_float4(0.f, 0.f, 0.f, 0.f);
        if (((unsigned)gy < IMG_H) && ((unsigned)gx < IMG_W))
            v = *(const float4*)&img[(size_t)gy * IMG_W + gx];
        *(float4*)&tile[r * LDS_W + cb] = v;
    }

    __syncthreads();   // drains vmcnt (global_load_lds) + lgkmcnt

    // ---- compute: 4x x 4y outputs per thread, 6 ds_read_b64 per row ----
    const int lx = lane * 4;        // output x within tile
    const int rbase = wave * 4;

    // Laundered 8-byte deltas: opaque to the vectorizer -> loads cannot be
    // proven adjacent -> stay as individual b64 (the conflict-free width).
    int d[6];
    #pragma unroll
    for (int t = 0; t < 6; ++t) {
        d[t] = t * 8;
        asm volatile("" : "+v"(d[t]));
    }

    const char* tb = (const char*)tile + (size_t)(rbase * LDS_W + lx) * 4;

    float acc[4][4] = {};

    #pragma unroll
    for (int r = 0; r < 10; ++r) {
        const char* rowb = tb + (size_t)r * (LDS_W * 4);
        float2 q[6];
        #pragma unroll
        for (int t = 0; t < 6; ++t)
            q[t] = *(const float2*)(rowb + d[t]);
        const float row[12] = {q[0].x, q[0].y, q[1].x, q[1].y,
                               q[2].x, q[2].y, q[3].x, q[3].y,
                               q[4].x, q[4].y, q[5].x, q[5].y};
        #pragma unroll
        for (int j = 0; j < 4; ++j) {
            const int ky = r - j;
            if (ky >= 0 && ky < 7) {
                #pragma unroll
                for (int kx = 0; kx < 7; ++kx) {
                    const float wv = w[ky * 7 + kx];
                    #pragma unroll
                    for (int cc = 0; cc < 4; ++cc)
                        acc[j][cc] = fmaf(row[1 + kx + cc], wv, acc[j][cc]);
                }
            }
        }
    }

    // ---- store: 4 rows of float4 per thread (contiguous per wave) ----
    float* o = out + (size_t)n * (IMG_W * IMG_H);
    #pragma unroll
    for (int j = 0; j < 4; ++j) {
        float4 v = make_float4(acc[j][0], acc[j][1], acc[j][2], acc[j][3]);
        *(float4*)&o[(size_t)(by + rbase + j) * IMG_W + bx + lx] = v;
    }
}

extern "C" void kernel_launch(void* const* d_in, const int* in_sizes, int n_in,
                              void* d_out, int out_size, void* d_ws, size_t ws_size,
                              hipStream_t stream)
{
    const float* x   = (const float*)d_in[0];
    const float* wgt = (const float*)d_in[1];
    float* out       = (float*)d_out;

    dim3 grid(IMG_W / TW, IMG_H / TH, NIMG);   // 2 x 32 x 64 = 4096 blocks
    conv7x7_kernel<<<grid, 256, 0, stream>>>(x, wgt, out);
}